// Round 1
// 1092.042 us; speedup vs baseline: 2.4215x; 2.4215x over previous
//
#include <hip/hip_runtime.h>

// GraphNetworkMetaLayer on MI355X (gfx950).
// Edge model rewritten on MFMA (v_mfma_f32_16x16x32_bf16, bf16 in / f32 acc).
// d_out layout (fp32): node_out [N,32] | edge_out [E,32] | global_out [32].
// f32 accumulators in module __device__ statics, zeroed each launch.

#define NMAX 100000

__device__ float g_agg[NMAX * 32];   // 12.8 MB
__device__ float g_cnt[NMAX];        // 0.4 MB
__device__ float g_gsum[32];

typedef __attribute__((ext_vector_type(8))) short bf16x8;   // 8 bf16 = 4 VGPRs
typedef __attribute__((ext_vector_type(4))) float f32x4;    // MFMA C/D

static __device__ __forceinline__ float us2f(unsigned short u) {
  union { unsigned int u32; float f; } c;
  c.u32 = ((unsigned int)u) << 16;
  return c.f;
}
// fp32 -> bf16 raw bits, round-to-nearest-even (finite inputs).
static __device__ __forceinline__ unsigned short f2us(float f) {
  union { float f; unsigned int u; } c;
  c.f = f;
  const unsigned int r = 0x7FFFu + ((c.u >> 16) & 1u);
  return (unsigned short)((c.u + r) >> 16);
}

// Swizzled LDS byte offset for a [rows][128 bf16] tile (256 B rows).
// XOR of bits 4-6 by (row&7) -> stride-256B column reads become ~2-way (free).
static __device__ __forceinline__ int swz(int R, int kb) {
  return (R << 8) + (kb ^ ((R & 7) << 4));
}

// ---------------- zero the accumulators (every call; statics persist) -------
__global__ __launch_bounds__(256) void zero_kernel() {
  const int i = blockIdx.x * 256 + threadIdx.x;
  if (i < NMAX * 32) g_agg[i] = 0.f;
  if (i < NMAX) g_cnt[i] = 0.f;
  if (i < 32) g_gsum[i] = 0.f;
}

// ---------------- edge model: MLP([x_src, x_dst, edge_attr, g]) -------------
// Persistent blocks. 256 threads = 4 waves; each wave owns 32 edges per tile
// (two 16-row M-tiles). Weights staged to LDS in B-frag layout once per block.
// No __syncthreads in the tile loop: all per-tile LDS state is wave-private.
__global__ __launch_bounds__(256, 2) void edge_kernel(
    const float* __restrict__ x,
    const int* __restrict__ eidx,          // [2][E]: row (src) then col (dst)
    const float* __restrict__ edge_attr,
    const float* __restrict__ gattr,
    const float* __restrict__ W1,   // [128][128] (k-major)
    const float* __restrict__ b1,   // [128]
    const float* __restrict__ W2,   // [128][32]
    const float* __restrict__ b2,   // [32]
    float* __restrict__ edge_out,   // [E][32]
    const int E, const int ntiles)
{
  __shared__ short s_W1t[128 * 128];      // W1^T [n][k] bf16, swizzled: 32 KB
  __shared__ short s_W2t[32 * 128];       // W2^T [n][k] bf16, swizzled:  8 KB
  __shared__ short s_inh[4 * 32 * 128];   // per-wave in/h (aliased):    32 KB
  __shared__ float s_b1[128];
  __shared__ float s_b2[32];
  // total ~73 KB -> 2 blocks/CU

  const int t = threadIdx.x;

  // ---- one-time weight staging: fp32 [k][n] -> bf16 [n][k] swizzled ----
  {
    const float4* w1s = (const float4*)W1;   // 4096 float4
    char* b = (char*)s_W1t;
#pragma unroll
    for (int i = 0; i < 16; ++i) {
      const int idx = t + 256 * i;
      const int k = idx >> 5, n = (idx & 31) * 4;
      const float4 f = w1s[idx];
      *(short*)(b + swz(n + 0, 2 * k)) = (short)f2us(f.x);
      *(short*)(b + swz(n + 1, 2 * k)) = (short)f2us(f.y);
      *(short*)(b + swz(n + 2, 2 * k)) = (short)f2us(f.z);
      *(short*)(b + swz(n + 3, 2 * k)) = (short)f2us(f.w);
    }
    const float4* w2s = (const float4*)W2;   // 1024 float4
    char* b2p = (char*)s_W2t;
#pragma unroll
    for (int i = 0; i < 4; ++i) {
      const int idx = t + 256 * i;
      const int k = idx >> 3, n = (idx & 7) * 4;
      const float4 f = w2s[idx];
      *(short*)(b2p + swz(n + 0, 2 * k)) = (short)f2us(f.x);
      *(short*)(b2p + swz(n + 1, 2 * k)) = (short)f2us(f.y);
      *(short*)(b2p + swz(n + 2, 2 * k)) = (short)f2us(f.z);
      *(short*)(b2p + swz(n + 3, 2 * k)) = (short)f2us(f.w);
    }
    if (t < 128) s_b1[t] = b1[t];
    else if (t < 160) s_b2[t - 128] = b2[t - 128];
  }
  __syncthreads();

  const int wave = t >> 6;
  const int lane = t & 63;
  const int q = lane & 15;        // fragment row/col index
  const int esub = lane >> 4;     // 0..3: k-group / acc row group
  char* const inh = (char*)s_inh;
  char* const w1b = (char*)s_W1t;
  char* const w2b = (char*)s_W2t;

  for (int tile = blockIdx.x; tile < ntiles; tile += gridDim.x) {
    const int ebase = tile * 128 + wave * 32;   // this wave's first edge

    // ---- stage e_in = [x_src|x_dst|edge_attr|g] : 32 rows x 128 bf16 ----
    // seg q covers cols 8q..8q+7; 16 lanes cover one edge; 4 edges/iter.
#pragma unroll
    for (int i = 0; i < 8; ++i) {
      const int rloc = i * 4 + esub;
      const int ge = ebase + rloc;
      float4 f0 = make_float4(0.f, 0.f, 0.f, 0.f);
      float4 f1 = f0;
      if (ge < E) {
        const float* src;
        if (q < 4)       src = x + (size_t)eidx[ge] * 32 + q * 8;
        else if (q < 8)  src = x + (size_t)eidx[(size_t)E + ge] * 32 + (q - 4) * 8;
        else if (q < 12) src = edge_attr + (size_t)ge * 32 + (q - 8) * 8;
        else             src = gattr + (q - 12) * 8;
        f0 = ((const float4*)src)[0];
        f1 = ((const float4*)src)[1];
      }
      bf16x8 u;
      u[0] = (short)f2us(f0.x); u[1] = (short)f2us(f0.y);
      u[2] = (short)f2us(f0.z); u[3] = (short)f2us(f0.w);
      u[4] = (short)f2us(f1.x); u[5] = (short)f2us(f1.y);
      u[6] = (short)f2us(f1.z); u[7] = (short)f2us(f1.w);
      *(bf16x8*)(inh + swz(wave * 32 + rloc, q * 16)) = u;
    }

    // ---- A1 fragments to registers (rows stay valid under h overwrite) ----
    bf16x8 a[2][4];
#pragma unroll
    for (int m = 0; m < 2; ++m)
#pragma unroll
      for (int kk = 0; kk < 4; ++kk)
        a[m][kk] = *(const bf16x8*)(inh + swz(wave * 32 + m * 16 + q,
                                              kk * 64 + esub * 16));

    // ---- layer 1: per n0-tile MFMA, relu, h -> LDS (overwrites e_in) ----
#pragma unroll
    for (int n0 = 0; n0 < 8; ++n0) {
      const int n = n0 * 16 + q;
      const float bias = s_b1[n];
      f32x4 acc0 = {bias, bias, bias, bias};
      f32x4 acc1 = acc0;
#pragma unroll
      for (int kk = 0; kk < 4; ++kk) {
        const bf16x8 bw = *(const bf16x8*)(w1b + swz(n, kk * 64 + esub * 16));
        acc0 = __builtin_amdgcn_mfma_f32_16x16x32_bf16(a[0][kk], bw, acc0, 0, 0, 0);
        acc1 = __builtin_amdgcn_mfma_f32_16x16x32_bf16(a[1][kk], bw, acc1, 0, 0, 0);
      }
      // D layout: row = esub*4+rr, col = n. Write h[row][n] (bf16, swizzled).
#pragma unroll
      for (int rr = 0; rr < 4; ++rr) {
        const int r0 = esub * 4 + rr;
        *(short*)(inh + swz(wave * 32 + r0, 2 * n)) =
            (short)f2us(fmaxf(acc0[rr], 0.f));
        *(short*)(inh + swz(wave * 32 + 16 + r0, 2 * n)) =
            (short)f2us(fmaxf(acc1[rr], 0.f));
      }
    }

    // ---- A2 fragments (h) ----
    bf16x8 h[2][4];
#pragma unroll
    for (int m = 0; m < 2; ++m)
#pragma unroll
      for (int kk = 0; kk < 4; ++kk)
        h[m][kk] = *(const bf16x8*)(inh + swz(wave * 32 + m * 16 + q,
                                              kk * 64 + esub * 16));

    // ---- layer 2 (2 n0-tiles) + epilogue: store, scatter-add ----
#pragma unroll
    for (int n0 = 0; n0 < 2; ++n0) {
      const int f = n0 * 16 + q;
      const float bias = s_b2[f];
      f32x4 acc0 = {bias, bias, bias, bias};
      f32x4 acc1 = acc0;
#pragma unroll
      for (int kk = 0; kk < 4; ++kk) {
        const bf16x8 bw = *(const bf16x8*)(w2b + swz(f, kk * 64 + esub * 16));
        acc0 = __builtin_amdgcn_mfma_f32_16x16x32_bf16(h[0][kk], bw, acc0, 0, 0, 0);
        acc1 = __builtin_amdgcn_mfma_f32_16x16x32_bf16(h[1][kk], bw, acc1, 0, 0, 0);
      }
#pragma unroll
      for (int rr = 0; rr < 4; ++rr) {
        const int ge0 = ebase + esub * 4 + rr;
        if (ge0 < E) {
          edge_out[(size_t)ge0 * 32 + f] = acc0[rr];
          const int dst = eidx[(size_t)E + ge0];
          atomicAdd(&g_agg[(size_t)dst * 32 + f], acc0[rr]);
          if (n0 == 0 && q == 0) atomicAdd(&g_cnt[dst], 1.0f);
        }
        const int ge1 = ebase + 16 + esub * 4 + rr;
        if (ge1 < E) {
          edge_out[(size_t)ge1 * 32 + f] = acc1[rr];
          const int dst = eidx[(size_t)E + ge1];
          atomicAdd(&g_agg[(size_t)dst * 32 + f], acc1[rr]);
          if (n0 == 0 && q == 0) atomicAdd(&g_cnt[dst], 1.0f);
        }
      }
    }
  }
}

// ---------------- node model: MLP([x, agg, g]) + partial sums for mean ------
__global__ __launch_bounds__(256) void node_kernel(
    const float* __restrict__ x,
    const float* __restrict__ gattr,
    const float* __restrict__ W1,   // [96][128]
    const float* __restrict__ b1,   // [128]
    const float* __restrict__ W2,   // [128][32]
    const float* __restrict__ b2,   // [32]
    float* __restrict__ node_out,   // [N][32]
    const int N)
{
  __shared__ __align__(16) unsigned short s_in[32][104];
  __shared__ __align__(16) unsigned short s_h[32][136];
  __shared__ __align__(16) unsigned short s_W1[96 * 128];
  __shared__ __align__(16) unsigned short s_W2[128 * 32];
  __shared__ float s_b1[128];
  __shared__ float s_b2[32];
  __shared__ float s_bsum[32];

  const int t = threadIdx.x;
  const int n0 = blockIdx.x * 32;

  {
    const float4* w1s = (const float4*)W1;
#pragma unroll
    for (int i = 0; i < 12; ++i) {
      const int idx = t + 256 * i;
      const float4 f = w1s[idx];
      ushort4 u; u.x = f2us(f.x); u.y = f2us(f.y); u.z = f2us(f.z); u.w = f2us(f.w);
      *(ushort4*)&s_W1[idx * 4] = u;
    }
    const float4* w2s = (const float4*)W2;
#pragma unroll
    for (int i = 0; i < 4; ++i) {
      const int idx = t + 256 * i;
      const float4 f = w2s[idx];
      ushort4 u; u.x = f2us(f.x); u.y = f2us(f.y); u.z = f2us(f.z); u.w = f2us(f.w);
      *(ushort4*)&s_W2[idx * 4] = u;
    }
    if (t < 128) s_b1[t] = b1[t];
    else if (t < 160) s_b2[t - 128] = b2[t - 128];
    else if (t < 192) s_bsum[t - 160] = 0.f;
  }

  {
    const int n = t >> 3;
    const int gn = n0 + n;
    const int kb = (t & 7) * 12;
    if (gn < N) {
      const float inv = 1.0f / fmaxf(g_cnt[gn], 1.0f);
#pragma unroll
      for (int kk = 0; kk < 12; ++kk) {
        const int k = kb + kk;
        float v;
        if (k < 32)      v = x[(size_t)gn * 32 + k];
        else if (k < 64) v = g_agg[(size_t)gn * 32 + (k - 32)] * inv;
        else             v = gattr[k - 64];
        s_in[n][k] = f2us(v);
      }
    } else {
#pragma unroll
      for (int kk = 0; kk < 12; ++kk) s_in[n][kb + kk] = 0;
    }
  }
  __syncthreads();

  {
    const int j0 = (t & 31) * 4;
    const int eb = (t >> 5) * 4;
    float acc[4][4];
#pragma unroll
    for (int i = 0; i < 4; ++i)
#pragma unroll
      for (int j = 0; j < 4; ++j) acc[i][j] = s_b1[j0 + j];
#pragma unroll 4
    for (int k = 0; k < 96; ++k) {
      const float a0 = us2f(s_in[eb + 0][k]);
      const float a1 = us2f(s_in[eb + 1][k]);
      const float a2 = us2f(s_in[eb + 2][k]);
      const float a3 = us2f(s_in[eb + 3][k]);
      const ushort4 w = *(const ushort4*)&s_W1[k * 128 + j0];
      const float w0 = us2f(w.x), w1v = us2f(w.y), w2v = us2f(w.z), w3v = us2f(w.w);
      acc[0][0] += a0 * w0; acc[0][1] += a0 * w1v; acc[0][2] += a0 * w2v; acc[0][3] += a0 * w3v;
      acc[1][0] += a1 * w0; acc[1][1] += a1 * w1v; acc[1][2] += a1 * w2v; acc[1][3] += a1 * w3v;
      acc[2][0] += a2 * w0; acc[2][1] += a2 * w1v; acc[2][2] += a2 * w2v; acc[2][3] += a2 * w3v;
      acc[3][0] += a3 * w0; acc[3][1] += a3 * w1v; acc[3][2] += a3 * w2v; acc[3][3] += a3 * w3v;
    }
#pragma unroll
    for (int i = 0; i < 4; ++i) {
      ushort4 r;
      r.x = f2us(fmaxf(acc[i][0], 0.f));
      r.y = f2us(fmaxf(acc[i][1], 0.f));
      r.z = f2us(fmaxf(acc[i][2], 0.f));
      r.w = f2us(fmaxf(acc[i][3], 0.f));
      *(ushort4*)&s_h[eb + i][j0] = r;
    }
  }
  __syncthreads();

  {
    const int n = t >> 3;
    const int f0 = (t & 7) * 4;
    float acc2[4] = { s_b2[f0 + 0], s_b2[f0 + 1], s_b2[f0 + 2], s_b2[f0 + 3] };
#pragma unroll 4
    for (int j = 0; j < 128; ++j) {
      const float hv = us2f(s_h[n][j]);
      const ushort4 w = *(const ushort4*)&s_W2[j * 32 + f0];
      acc2[0] += hv * us2f(w.x);
      acc2[1] += hv * us2f(w.y);
      acc2[2] += hv * us2f(w.z);
      acc2[3] += hv * us2f(w.w);
    }
    const int gn = n0 + n;
    if (gn < N) {
      float4 o = make_float4(acc2[0], acc2[1], acc2[2], acc2[3]);
      *(float4*)&node_out[(size_t)gn * 32 + f0] = o;
      atomicAdd(&s_bsum[f0 + 0], acc2[0]);
      atomicAdd(&s_bsum[f0 + 1], acc2[1]);
      atomicAdd(&s_bsum[f0 + 2], acc2[2]);
      atomicAdd(&s_bsum[f0 + 3], acc2[3]);
    }
  }
  __syncthreads();
  if (t < 32) atomicAdd(&g_gsum[t], s_bsum[t]);
}

// ---------------- global model: MLP([mean(node_out), g]) --------------------
__global__ __launch_bounds__(128) void global_kernel(
    const float* __restrict__ gattr,
    const float* __restrict__ W1,   // [64][128]
    const float* __restrict__ b1,   // [128]
    const float* __restrict__ W2,   // [128][32]
    const float* __restrict__ b2,   // [32]
    float* __restrict__ gout,       // [32]
    const int N)
{
  __shared__ float s_gin[64];
  __shared__ float s_h[128];
  const int t = threadIdx.x;
  if (t < 32) s_gin[t] = g_gsum[t] / (float)N;
  else if (t < 64) s_gin[t] = gattr[t - 32];
  __syncthreads();
  {
    float a = b1[t];
#pragma unroll 4
    for (int k = 0; k < 64; ++k) a += s_gin[k] * W1[k * 128 + t];
    s_h[t] = fmaxf(a, 0.f);
  }
  __syncthreads();
  if (t < 32) {
    float o = b2[t];
#pragma unroll 4
    for (int j = 0; j < 128; ++j) o += s_h[j] * W2[j * 32 + t];
    gout[t] = o;
  }
}

extern "C" void kernel_launch(void* const* d_in, const int* in_sizes, int n_in,
                              void* d_out, int out_size, void* d_ws, size_t ws_size,
                              hipStream_t stream)
{
  const float* x         = (const float*)d_in[0];
  const int*   eidx      = (const int*)d_in[1];
  const float* edge_attr = (const float*)d_in[2];
  const float* gattr     = (const float*)d_in[3];
  const float* W1e = (const float*)d_in[4];
  const float* b1e = (const float*)d_in[5];
  const float* W2e = (const float*)d_in[6];
  const float* b2e = (const float*)d_in[7];
  const float* W1n = (const float*)d_in[8];
  const float* b1n = (const float*)d_in[9];
  const float* W2n = (const float*)d_in[10];
  const float* b2n = (const float*)d_in[11];
  const float* W1g = (const float*)d_in[12];
  const float* b1g = (const float*)d_in[13];
  const float* W2g = (const float*)d_in[14];
  const float* b2g = (const float*)d_in[15];

  const int N = in_sizes[0] / 32;
  const int E = in_sizes[2] / 32;

  float* node_out = (float*)d_out;
  float* edge_out = node_out + (size_t)N * 32;
  float* gout     = edge_out + (size_t)E * 32;

  const int ntiles = (E + 127) >> 7;
  const int nblk = ntiles < 512 ? ntiles : 512;

  zero_kernel<<<dim3((NMAX * 32 + 255) / 256), dim3(256), 0, stream>>>();
  edge_kernel<<<dim3(nblk), dim3(256), 0, stream>>>(
      x, eidx, edge_attr, gattr, W1e, b1e, W2e, b2e, edge_out, E, ntiles);
  node_kernel<<<dim3((N + 31) / 32), dim3(256), 0, stream>>>(
      x, gattr, W1n, b1n, W2n, b2n, node_out, N);
  global_kernel<<<dim3(1), dim3(128), 0, stream>>>(
      gattr, W1g, b1g, W2g, b2g, gout, N);
}